// Round 5
// baseline (2076.410 us; speedup 1.0000x reference)
//
#include <hip/hip_runtime.h>
#include <math.h>

// Sliced Wasserstein-2: for each (b,c,p): W2^2 = mean_i (sort(X@theta_p) - sort(Y@theta_p))^2
// loss = mean_{b,c} sqrt(mean_p W2^2)
//
// R5: register-resident bitonic (R2) + amdgpu_num_vgpr(128): pin the register
// BUDGET directly. R3 (__launch_bounds__ min-waves) and R4 (waves_per_eu(4,4))
// both left the allocator at 64 VGPRs -> ~1.4GB/dispatch scratch round-trip of
// sx[]/v[] around the 10 wave-crossing LDS stages (= the whole runtime).
// 128 = 512/4 is the max that keeps 16 waves (one 1024-thr block) resident,
// and 128KB dynamic LDS already caps us at 1 block/CU, so zero occupancy cost.

namespace {
constexpr int Bb = 8, Cc = 4, Nn = 32768, Pp = 50;
constexpr int THREADS = 1024;
constexpr int VPT = 32;                    // values per thread
constexpr int SLICES = Bb * Cc * Pp;       // 1600
}

__device__ __forceinline__ void ce(float& a, float& b, bool up) {
  float lo = fminf(a, b);
  float hi = fmaxf(a, b);
  a = up ? lo : hi;
  b = up ? hi : lo;
}

// Full bitonic sort of the distributed array v[] (32768 elems over 1024 threads).
// s = 128KB LDS scratch for the 10 wave-crossing stages.
__device__ __forceinline__ void sort_dist(float v[VPT], float* s, int tid) {
  // ---- phase 1: k = 2..32, all j <= 16 in-register ----
#pragma unroll
  for (int k = 2; k <= VPT; k <<= 1) {
#pragma unroll
    for (int j = k >> 1; j > 0; j >>= 1) {
#pragma unroll
      for (int r = 0; r < VPT; r++) {
        if ((r & j) == 0) {
          bool up = (((tid * VPT + r) & k) == 0);
          ce(v[r], v[r | j], up);
        }
      }
    }
  }
  // ---- phase 2: k = 64..32768 ----
  for (int k = 64; k <= Nn; k <<= 1) {
    const bool up = (((tid * VPT) & k) == 0);   // uniform over this thread's 32 elems
    // cross-thread stages: j = k/2 .. 32
    for (int j = k >> 1; j >= VPT; j >>= 1) {
      const int m = j / VPT;                    // partner tid xor-mask, 1..512
      const bool keepMin = (up == ((tid & m) == 0));
      if (m < 64) {
        // partner in same wave64: shuffle exchange, no barrier, no bank conflicts
#pragma unroll
        for (int r = 0; r < VPT; r++) {
          float o = __shfl_xor(v[r], m, 64);
          v[r] = keepMin ? fminf(v[r], o) : fmaxf(v[r], o);
        }
      } else {
        // wave-crossing: LDS exchange, column layout s[r*THREADS + tid]
        __syncthreads();                        // prior stage's reads must finish
#pragma unroll
        for (int r = 0; r < VPT; r++) s[r * THREADS + tid] = v[r];
        __syncthreads();
        const int pt = tid ^ m;
#pragma unroll
        for (int r = 0; r < VPT; r++) {
          float o = s[r * THREADS + pt];
          v[r] = keepMin ? fminf(v[r], o) : fmaxf(v[r], o);
        }
      }
    }
    // in-register tail: j = 16..1, direction uniform per thread
#pragma unroll
    for (int j = VPT >> 1; j > 0; j >>= 1) {
#pragma unroll
      for (int r = 0; r < VPT; r++) {
        if ((r & j) == 0) ce(v[r], v[r | j], up);
      }
    }
  }
}

extern "C" __global__
__attribute__((amdgpu_flat_work_group_size(1024, 1024),
               amdgpu_waves_per_eu(4, 4),
               amdgpu_num_vgpr(128)))
void swd_slice(const float* __restrict__ x, const float* __restrict__ y,
               const float* __restrict__ proj, float* __restrict__ w2) {
  extern __shared__ float s[];               // Nn floats = 128 KB
  __shared__ float wsum[THREADS / 64];
  const int slice = blockIdx.x;
  const int p  = slice % Pp;
  const int bc = slice / Pp;
  const int tid = threadIdx.x;
  const float t0 = proj[2 * p];
  const float t1 = proj[2 * p + 1];
  // D=2: one float4 = two consecutive points
  const float4* xb = (const float4*)(x + (size_t)bc * Nn * 2);
  const float4* yb = (const float4*)(y + (size_t)bc * Nn * 2);

  float v[VPT], sx[VPT];

  // ---- project X (thread t owns points tid*32 .. tid*32+31), sort ----
#pragma unroll
  for (int q = 0; q < VPT / 2; q++) {
    float4 u = xb[tid * (VPT / 2) + q];
    v[2 * q]     = fmaf(u.x, t0, u.y * t1);
    v[2 * q + 1] = fmaf(u.z, t0, u.w * t1);
  }
  sort_dist(v, s, tid);
#pragma unroll
  for (int r = 0; r < VPT; r++) sx[r] = v[r];   // sorted X stays in registers

  // ---- project Y, sort ----
#pragma unroll
  for (int q = 0; q < VPT / 2; q++) {
    float4 u = yb[tid * (VPT / 2) + q];
    v[2 * q]     = fmaf(u.x, t0, u.y * t1);
    v[2 * q + 1] = fmaf(u.z, t0, u.w * t1);
  }
  sort_dist(v, s, tid);

  // ---- sum of squared diffs of matched order statistics ----
  float acc = 0.f;
#pragma unroll
  for (int r = 0; r < VPT; r++) {
    float d = sx[r] - v[r];
    acc = fmaf(d, d, acc);
  }
#pragma unroll
  for (int off = 32; off > 0; off >>= 1)
    acc += __shfl_down(acc, off, 64);
  if ((tid & 63) == 0) wsum[tid >> 6] = acc;
  __syncthreads();
  if (tid == 0) {
    float t = 0.f;
#pragma unroll
    for (int w = 0; w < THREADS / 64; w++) t += wsum[w];
    w2[slice] = t * (1.0f / Nn);               // mean over N
  }
}

extern "C" __global__ void swd_final(const float* __restrict__ w2,
                                     float* __restrict__ out) {
  __shared__ float sred[Bb * Cc];
  int t = threadIdx.x;
  if (t < Bb * Cc) {
    float sum = 0.f;
    for (int p = 0; p < Pp; p++) sum += w2[t * Pp + p];
    sred[t] = sqrtf(sum * (1.0f / Pp));        // SWD per (b,c)
  }
  __syncthreads();
  if (t == 0) {
    float a = 0.f;
    for (int i = 0; i < Bb * Cc; i++) a += sred[i];
    out[0] = a * (1.0f / (Bb * Cc));           // mean over (b,c)
  }
}

extern "C" void kernel_launch(void* const* d_in, const int* in_sizes, int n_in,
                              void* d_out, int out_size, void* d_ws, size_t ws_size,
                              hipStream_t stream) {
  const float* x    = (const float*)d_in[0];   // output [B,C,N,D] fp32
  const float* y    = (const float*)d_in[1];   // target [B,C,N,D] fp32
  const float* proj = (const float*)d_in[2];   // projections [P,D] fp32
  float* w2  = (float*)d_ws;                   // [SLICES] fp32 scratch
  float* out = (float*)d_out;

  (void)hipFuncSetAttribute((const void*)swd_slice,
                            hipFuncAttributeMaxDynamicSharedMemorySize,
                            Nn * (int)sizeof(float));

  hipLaunchKernelGGL(swd_slice, dim3(SLICES), dim3(THREADS),
                     Nn * sizeof(float), stream, x, y, proj, w2);
  hipLaunchKernelGGL(swd_final, dim3(1), dim3(64), 0, stream, w2, out);
}

// Round 6
// 1876.247 us; speedup vs baseline: 1.1067x; 1.1067x over previous
//
#include <hip/hip_runtime.h>
#include <math.h>

// Sliced Wasserstein-2: for each (b,c,p): W2^2 = mean_i (sort(X@theta_p) - sort(Y@theta_p))^2
// loss = mean_{b,c} sqrt(mean_p W2^2)
//
// R6: the 1024-thread register budget is hard-capped at 64 VGPRs (R3/R4/R5:
// launch_bounds, waves_per_eu, amdgpu_num_vgpr all ignored -> 1.4GB/dispatch
// scratch spill of sx[]+v[]). Fix by restructuring: TWO kernels, each with
// live set v[32]+temps < 64. Kernel A sorts X and stages the sorted run in
// d_ws (210MB, mostly L3-resident); kernel B sorts Y, streams sorted X back,
// reduces. Host chunks over slices if ws_size is small; falls back to the
// fused kernel if ws_size can't hold even one slice.

namespace {
constexpr int Bb = 8, Cc = 4, Nn = 32768, Pp = 50;
constexpr int THREADS = 1024;
constexpr int VPT = 32;                    // values per thread
constexpr int SLICES = Bb * Cc * Pp;       // 1600
constexpr size_t W2_BYTES = 8192;          // w2[1600] rounded up
}

__device__ __forceinline__ void ce(float& a, float& b, bool up) {
  float lo = fminf(a, b);
  float hi = fmaxf(a, b);
  a = up ? lo : hi;
  b = up ? hi : lo;
}

// Full bitonic sort of the distributed array v[] (32768 elems over 1024 threads).
// s = 128KB LDS scratch for the 10 wave-crossing stages. Rank of v[r] = tid*32+r.
__device__ __forceinline__ void sort_dist(float v[VPT], float* s, int tid) {
  // ---- phase 1: k = 2..32, all j <= 16 in-register ----
#pragma unroll
  for (int k = 2; k <= VPT; k <<= 1) {
#pragma unroll
    for (int j = k >> 1; j > 0; j >>= 1) {
#pragma unroll
      for (int r = 0; r < VPT; r++) {
        if ((r & j) == 0) {
          bool up = (((tid * VPT + r) & k) == 0);
          ce(v[r], v[r | j], up);
        }
      }
    }
  }
  // ---- phase 2: k = 64..32768 ----
  for (int k = 64; k <= Nn; k <<= 1) {
    const bool up = (((tid * VPT) & k) == 0);   // uniform over this thread's 32 elems
    for (int j = k >> 1; j >= VPT; j >>= 1) {
      const int m = j / VPT;                    // partner tid xor-mask, 1..512
      const bool keepMin = (up == ((tid & m) == 0));
      if (m < 64) {
        // same-wave partner: shuffle exchange, no barrier
#pragma unroll
        for (int r = 0; r < VPT; r++) {
          float o = __shfl_xor(v[r], m, 64);
          v[r] = keepMin ? fminf(v[r], o) : fmaxf(v[r], o);
        }
      } else {
        // wave-crossing: LDS exchange, column layout s[r*THREADS + tid]
        __syncthreads();
#pragma unroll
        for (int r = 0; r < VPT; r++) s[r * THREADS + tid] = v[r];
        __syncthreads();
        const int pt = tid ^ m;
#pragma unroll
        for (int r = 0; r < VPT; r++) {
          float o = s[r * THREADS + pt];
          v[r] = keepMin ? fminf(v[r], o) : fmaxf(v[r], o);
        }
      }
    }
    // in-register tail: j = 16..1
#pragma unroll
    for (int j = VPT >> 1; j > 0; j >>= 1) {
#pragma unroll
      for (int r = 0; r < VPT; r++) {
        if ((r & j) == 0) ce(v[r], v[r | j], up);
      }
    }
  }
}

__device__ __forceinline__ void project_slice(const float4* base, float t0, float t1,
                                              int tid, float v[VPT]) {
#pragma unroll
  for (int q = 0; q < VPT / 2; q++) {
    float4 u = base[tid * (VPT / 2) + q];
    v[2 * q]     = fmaf(u.x, t0, u.y * t1);
    v[2 * q + 1] = fmaf(u.z, t0, u.w * t1);
  }
}

// ---- kernel A: sort X slice, stage sorted run in scratch ----
extern "C" __global__ void __launch_bounds__(THREADS)
swd_sortx(const float* __restrict__ x, const float* __restrict__ proj,
          float* __restrict__ xs, int slice_base) {
  extern __shared__ float s[];
  const int slice = slice_base + blockIdx.x;
  const int p  = slice % Pp;
  const int bc = slice / Pp;
  const int tid = threadIdx.x;
  const float t0 = proj[2 * p];
  const float t1 = proj[2 * p + 1];
  float v[VPT];
  project_slice((const float4*)(x + (size_t)bc * Nn * 2), t0, t1, tid, v);
  sort_dist(v, s, tid);
  // store sorted (rank = tid*32+r), 128B per thread, coalesced float4
  float4* o = (float4*)(xs + (size_t)blockIdx.x * Nn + tid * VPT);
#pragma unroll
  for (int q = 0; q < VPT / 4; q++)
    o[q] = make_float4(v[4 * q], v[4 * q + 1], v[4 * q + 2], v[4 * q + 3]);
}

// ---- kernel B: sort Y slice, diff against staged sorted X, reduce ----
extern "C" __global__ void __launch_bounds__(THREADS)
swd_sorty(const float* __restrict__ y, const float* __restrict__ proj,
          const float* __restrict__ xs, float* __restrict__ w2, int slice_base) {
  extern __shared__ float s[];
  __shared__ float wsum[THREADS / 64];
  const int slice = slice_base + blockIdx.x;
  const int p  = slice % Pp;
  const int bc = slice / Pp;
  const int tid = threadIdx.x;
  const float t0 = proj[2 * p];
  const float t1 = proj[2 * p + 1];
  float v[VPT];
  project_slice((const float4*)(y + (size_t)bc * Nn * 2), t0, t1, tid, v);
  sort_dist(v, s, tid);

  const float4* xr = (const float4*)(xs + (size_t)blockIdx.x * Nn + tid * VPT);
  float acc = 0.f;
#pragma unroll
  for (int q = 0; q < VPT / 4; q++) {
    float4 u = xr[q];
    float d0 = u.x - v[4 * q];
    float d1 = u.y - v[4 * q + 1];
    float d2 = u.z - v[4 * q + 2];
    float d3 = u.w - v[4 * q + 3];
    acc = fmaf(d0, d0, acc);
    acc = fmaf(d1, d1, acc);
    acc = fmaf(d2, d2, acc);
    acc = fmaf(d3, d3, acc);
  }
#pragma unroll
  for (int off = 32; off > 0; off >>= 1)
    acc += __shfl_down(acc, off, 64);
  if ((tid & 63) == 0) wsum[tid >> 6] = acc;
  __syncthreads();
  if (tid == 0) {
    float t = 0.f;
#pragma unroll
    for (int w = 0; w < THREADS / 64; w++) t += wsum[w];
    w2[slice] = t * (1.0f / Nn);
  }
}

// ---- fallback fused kernel (R2): used only if ws_size is too small ----
extern "C" __global__ void __launch_bounds__(THREADS)
swd_slice(const float* __restrict__ x, const float* __restrict__ y,
          const float* __restrict__ proj, float* __restrict__ w2) {
  extern __shared__ float s[];
  __shared__ float wsum[THREADS / 64];
  const int slice = blockIdx.x;
  const int p  = slice % Pp;
  const int bc = slice / Pp;
  const int tid = threadIdx.x;
  const float t0 = proj[2 * p];
  const float t1 = proj[2 * p + 1];
  float v[VPT], sx[VPT];
  project_slice((const float4*)(x + (size_t)bc * Nn * 2), t0, t1, tid, v);
  sort_dist(v, s, tid);
#pragma unroll
  for (int r = 0; r < VPT; r++) sx[r] = v[r];
  project_slice((const float4*)(y + (size_t)bc * Nn * 2), t0, t1, tid, v);
  sort_dist(v, s, tid);
  float acc = 0.f;
#pragma unroll
  for (int r = 0; r < VPT; r++) {
    float d = sx[r] - v[r];
    acc = fmaf(d, d, acc);
  }
#pragma unroll
  for (int off = 32; off > 0; off >>= 1)
    acc += __shfl_down(acc, off, 64);
  if ((tid & 63) == 0) wsum[tid >> 6] = acc;
  __syncthreads();
  if (tid == 0) {
    float t = 0.f;
#pragma unroll
    for (int w = 0; w < THREADS / 64; w++) t += wsum[w];
    w2[slice] = t * (1.0f / Nn);
  }
}

extern "C" __global__ void swd_final(const float* __restrict__ w2,
                                     float* __restrict__ out) {
  __shared__ float sred[Bb * Cc];
  int t = threadIdx.x;
  if (t < Bb * Cc) {
    float sum = 0.f;
    for (int p = 0; p < Pp; p++) sum += w2[t * Pp + p];
    sred[t] = sqrtf(sum * (1.0f / Pp));
  }
  __syncthreads();
  if (t == 0) {
    float a = 0.f;
    for (int i = 0; i < Bb * Cc; i++) a += sred[i];
    out[0] = a * (1.0f / (Bb * Cc));
  }
}

extern "C" void kernel_launch(void* const* d_in, const int* in_sizes, int n_in,
                              void* d_out, int out_size, void* d_ws, size_t ws_size,
                              hipStream_t stream) {
  const float* x    = (const float*)d_in[0];
  const float* y    = (const float*)d_in[1];
  const float* proj = (const float*)d_in[2];
  float* w2  = (float*)d_ws;                       // first 8KB of scratch
  float* xs  = (float*)((char*)d_ws + W2_BYTES);   // sorted-X staging
  float* out = (float*)d_out;

  const size_t lds = Nn * sizeof(float);
  (void)hipFuncSetAttribute((const void*)swd_sortx,
                            hipFuncAttributeMaxDynamicSharedMemorySize, (int)lds);
  (void)hipFuncSetAttribute((const void*)swd_sorty,
                            hipFuncAttributeMaxDynamicSharedMemorySize, (int)lds);
  (void)hipFuncSetAttribute((const void*)swd_slice,
                            hipFuncAttributeMaxDynamicSharedMemorySize, (int)lds);

  const size_t slice_bytes = (size_t)Nn * sizeof(float);
  const size_t avail = ws_size > W2_BYTES ? ws_size - W2_BYTES : 0;
  int chunk = (int)(avail / slice_bytes);
  if (chunk > SLICES) chunk = SLICES;

  if (chunk >= 1) {
    for (int base = 0; base < SLICES; base += chunk) {
      int n = SLICES - base < chunk ? SLICES - base : chunk;
      hipLaunchKernelGGL(swd_sortx, dim3(n), dim3(THREADS), lds, stream,
                         x, proj, xs, base);
      hipLaunchKernelGGL(swd_sorty, dim3(n), dim3(THREADS), lds, stream,
                         y, proj, xs, w2, base);
    }
  } else {
    hipLaunchKernelGGL(swd_slice, dim3(SLICES), dim3(THREADS), lds, stream,
                       x, y, proj, w2);
  }
  hipLaunchKernelGGL(swd_final, dim3(1), dim3(64), 0, stream, w2, out);
}

// Round 7
// 1313.196 us; speedup vs baseline: 1.5812x; 1.4288x over previous
//
#include <hip/hip_runtime.h>
#include <math.h>

// Sliced Wasserstein-2: for each (b,c,p): W2^2 = mean_i (sort(X@theta_p) - sort(Y@theta_p))^2
// loss = mean_{b,c} sqrt(mean_p W2^2)
//
// R7: cut DS-pipe work of the distributed bitonic sort (R6 analysis: ~2080
// DS ops/thread/sort = the floor).
//  - m=1,2 lane exchanges via DPP quad_perm (VALU pipe, not DS): -608 bpermutes
//  - merges k=8192,16384,32768 via LDS bit-field transpose (reg <-> i[14:10]):
//    all b14..b10 stages become in-register w/ compile-time directions,
//    replacing 9 LDS-exchange stages + 3 m=32 bpermute stages with 6 transposes
//  - sign-flip trick for in-register tails (ascending-only networks)
// Two-kernel split from R6 retained (1024-thr register budget hard-capped at 64).

namespace {
constexpr int Bb = 8, Cc = 4, Nn = 32768, Pp = 50;
constexpr int THREADS = 1024;
constexpr int VPT = 32;                    // values per thread
constexpr int SLICES = Bb * Cc * Pp;       // 1600
constexpr size_t W2_BYTES = 8192;          // w2[1600] rounded up
constexpr int LDS_FLOATS = Nn + (Nn >> 5); // padded transpose buffer: 33792
}

__device__ __forceinline__ void ce(float& a, float& b, bool up) {
  float lo = fminf(a, b);
  float hi = fmaxf(a, b);
  a = up ? lo : hi;
  b = up ? hi : lo;
}

__device__ __forceinline__ float dpp_xor(float x, int ctrl_sel) {
  // ctrl_sel: 0xB1 = quad_perm(1,0,3,2) = xor1; 0x4E = quad_perm(2,3,0,1) = xor2
  int i = ctrl_sel == 0xB1
    ? __builtin_amdgcn_update_dpp(0, __float_as_int(x), 0xB1, 0xF, 0xF, true)
    : __builtin_amdgcn_update_dpp(0, __float_as_int(x), 0x4E, 0xF, 0xF, true);
  return __int_as_float(i);
}

// cross-lane CE stage with xor-mask M (M=1,2 via DPP; M>=4 via ds_bpermute)
template<int M>
__device__ __forceinline__ void stage_xlane(float v[VPT], int tid, bool up) {
  const bool keepMin = (up == ((tid & M) == 0));
  if constexpr (M == 1 || M == 2) {
    constexpr int ctrl = (M == 1) ? 0xB1 : 0x4E;
#pragma unroll
    for (int r = 0; r < VPT; r++) {
      float o = dpp_xor(v[r], ctrl);
      v[r] = keepMin ? fminf(v[r], o) : fmaxf(v[r], o);
    }
  } else {
    const int addr = (((tid & 63) ^ M) << 2);  // bpermute byte address (lane^M)
#pragma unroll
    for (int r = 0; r < VPT; r++) {
      float o = __int_as_float(
          __builtin_amdgcn_ds_bpermute(addr, __float_as_int(v[r])));
      v[r] = keepMin ? fminf(v[r], o) : fmaxf(v[r], o);
    }
  }
}

// in-register tail (stages j=16..1), direction uniform per thread: sign-flip trick
__device__ __forceinline__ void tail_inreg(float v[VPT], bool up) {
  const unsigned flip = up ? 0u : 0x80000000u;
#pragma unroll
  for (int r = 0; r < VPT; r++)
    v[r] = __int_as_float(__float_as_int(v[r]) ^ flip);
#pragma unroll
  for (int j = 16; j > 0; j >>= 1) {
#pragma unroll
    for (int r = 0; r < VPT; r++) {
      if (!(r & j)) {
        float a = v[r], b = v[r | j];
        v[r] = fminf(a, b);
        v[r | j] = fmaxf(a, b);
      }
    }
  }
#pragma unroll
  for (int r = 0; r < VPT; r++)
    v[r] = __int_as_float(__float_as_int(v[r]) ^ flip);
}

// wave-local cross stages (m = MTOP..1) + tail, for merge k = 2^A
template<int A, int MTOP>
__device__ __forceinline__ void wave_stages_and_tail(float v[VPT], int tid) {
  const bool up = (A == 15) ? true : ((tid & (1 << (A - 5))) == 0);
  if constexpr (MTOP >= 32) stage_xlane<32>(v, tid, up);
  if constexpr (MTOP >= 16) stage_xlane<16>(v, tid, up);
  if constexpr (MTOP >= 8)  stage_xlane<8>(v, tid, up);
  if constexpr (MTOP >= 4)  stage_xlane<4>(v, tid, up);
  if constexpr (MTOP >= 2)  stage_xlane<2>(v, tid, up);
  if constexpr (MTOP >= 1)  stage_xlane<1>(v, tid, up);
  tail_inreg(v, up);
}

// LDS-exchange stage (wave-crossing xor-mask m on tid), column layout
__device__ __forceinline__ void stage_lds(float v[VPT], float* s, int tid,
                                          int m, bool up) {
  const bool keepMin = (up == ((tid & m) == 0));
  __syncthreads();
#pragma unroll
  for (int r = 0; r < VPT; r++) s[r * THREADS + tid] = v[r];
  __syncthreads();
  const int pt = tid ^ m;
#pragma unroll
  for (int r = 0; r < VPT; r++) {
    float o = s[r * THREADS + pt];
    v[r] = keepMin ? fminf(v[r], o) : fmaxf(v[r], o);
  }
}

// Merge k=2^A (A=13..15), stages b=A-1..10 done in transposed layout:
// L2: element i = (r2<<10) | tid, so i[14:10] are register bits.
// Padded LDS addressing Adr(i) = i + (i>>5): all accesses <=2-way (free).
template<int A>
__device__ __forceinline__ void merge_high_l2(float v[VPT], float* s, int tid) {
  __syncthreads();                      // prior reads of s must be done
  const int base = tid * VPT;
#pragma unroll
  for (int r = 0; r < VPT; r++) {       // write layout L0 (rank-linear)
    int i = base + r;
    s[i + (i >> 5)] = v[r];
  }
  __syncthreads();
#pragma unroll
  for (int r2 = 0; r2 < VPT; r2++) {    // read layout L2
    int i = (r2 << 10) | tid;
    v[r2] = s[i + (i >> 5)];
  }
  // stages b = A-1 .. 10  (register bits A-11 .. 0); compile-time directions
#pragma unroll
  for (int bb = A - 11; bb >= 0; bb--) {
    const int j = 1 << bb;
#pragma unroll
    for (int r2 = 0; r2 < VPT; r2++) {
      if (!(r2 & j)) {
        bool upv = (A == 15) ? true : (((r2 >> (A - 10)) & 1) == 0);
        ce(v[r2], v[r2 | j], upv);
      }
    }
  }
  // note: no barrier needed here — each thread rewrites exactly the slots it read
#pragma unroll
  for (int r2 = 0; r2 < VPT; r2++) {    // write back in L2
    int i = (r2 << 10) | tid;
    s[i + (i >> 5)] = v[r2];
  }
  __syncthreads();
#pragma unroll
  for (int r = 0; r < VPT; r++) {       // read back in L0
    int i = base + r;
    v[r] = s[i + (i >> 5)];
  }
}

// Full distributed bitonic sort: rank of v[r] on thread tid is tid*32 + r.
__device__ __forceinline__ void sort_dist(float v[VPT], float* s, int tid) {
  // merges a=1..4 (k=2..16): in-register, compile-time directions
#pragma unroll
  for (int k = 2; k <= 16; k <<= 1) {
#pragma unroll
    for (int j = k >> 1; j > 0; j >>= 1) {
#pragma unroll
      for (int r = 0; r < VPT; r++)
        if (!(r & j)) ce(v[r], v[r | j], (r & k) == 0);
    }
  }
  // a=5 (k=32): dir = i bit5 = tid bit0, all stages in-register
  tail_inreg(v, (tid & 1) == 0);
  // a=6..11: wave-local exchanges + tail
  wave_stages_and_tail<6, 1>(v, tid);
  wave_stages_and_tail<7, 2>(v, tid);
  wave_stages_and_tail<8, 4>(v, tid);
  wave_stages_and_tail<9, 8>(v, tid);
  wave_stages_and_tail<10, 16>(v, tid);
  wave_stages_and_tail<11, 32>(v, tid);
  // a=12: one wave-crossing LDS stage (m=64), then wave-local
  stage_lds(v, s, tid, 64, (tid & 128) == 0);
  wave_stages_and_tail<12, 32>(v, tid);
  // a=13..15: transposed high stages, then wave-local (b9..b5 => m=16..1)
  merge_high_l2<13>(v, s, tid);
  wave_stages_and_tail<13, 16>(v, tid);
  merge_high_l2<14>(v, s, tid);
  wave_stages_and_tail<14, 16>(v, tid);
  merge_high_l2<15>(v, s, tid);
  wave_stages_and_tail<15, 16>(v, tid);
}

__device__ __forceinline__ void project_slice(const float4* base, float t0, float t1,
                                              int tid, float v[VPT]) {
#pragma unroll
  for (int q = 0; q < VPT / 2; q++) {
    float4 u = base[tid * (VPT / 2) + q];
    v[2 * q]     = fmaf(u.x, t0, u.y * t1);
    v[2 * q + 1] = fmaf(u.z, t0, u.w * t1);
  }
}

// ---- kernel A: sort X slice, stage sorted run in scratch ----
extern "C" __global__ void __launch_bounds__(THREADS)
swd_sortx(const float* __restrict__ x, const float* __restrict__ proj,
          float* __restrict__ xs, int slice_base) {
  extern __shared__ float s[];
  const int slice = slice_base + blockIdx.x;
  const int p  = slice % Pp;
  const int bc = slice / Pp;
  const int tid = threadIdx.x;
  const float t0 = proj[2 * p];
  const float t1 = proj[2 * p + 1];
  float v[VPT];
  project_slice((const float4*)(x + (size_t)bc * Nn * 2), t0, t1, tid, v);
  sort_dist(v, s, tid);
  float4* o = (float4*)(xs + (size_t)blockIdx.x * Nn + tid * VPT);
#pragma unroll
  for (int q = 0; q < VPT / 4; q++)
    o[q] = make_float4(v[4 * q], v[4 * q + 1], v[4 * q + 2], v[4 * q + 3]);
}

// ---- kernel B: sort Y slice, diff against staged sorted X, reduce ----
extern "C" __global__ void __launch_bounds__(THREADS)
swd_sorty(const float* __restrict__ y, const float* __restrict__ proj,
          const float* __restrict__ xs, float* __restrict__ w2, int slice_base) {
  extern __shared__ float s[];
  __shared__ float wsum[THREADS / 64];
  const int slice = slice_base + blockIdx.x;
  const int p  = slice % Pp;
  const int bc = slice / Pp;
  const int tid = threadIdx.x;
  const float t0 = proj[2 * p];
  const float t1 = proj[2 * p + 1];
  float v[VPT];
  project_slice((const float4*)(y + (size_t)bc * Nn * 2), t0, t1, tid, v);
  sort_dist(v, s, tid);

  const float4* xr = (const float4*)(xs + (size_t)blockIdx.x * Nn + tid * VPT);
  float acc = 0.f;
#pragma unroll
  for (int q = 0; q < VPT / 4; q++) {
    float4 u = xr[q];
    float d0 = u.x - v[4 * q];
    float d1 = u.y - v[4 * q + 1];
    float d2 = u.z - v[4 * q + 2];
    float d3 = u.w - v[4 * q + 3];
    acc = fmaf(d0, d0, acc);
    acc = fmaf(d1, d1, acc);
    acc = fmaf(d2, d2, acc);
    acc = fmaf(d3, d3, acc);
  }
#pragma unroll
  for (int off = 32; off > 0; off >>= 1)
    acc += __shfl_down(acc, off, 64);
  if ((tid & 63) == 0) wsum[tid >> 6] = acc;
  __syncthreads();
  if (tid == 0) {
    float t = 0.f;
#pragma unroll
    for (int w = 0; w < THREADS / 64; w++) t += wsum[w];
    w2[slice] = t * (1.0f / Nn);
  }
}

// ---- fallback fused kernel: used only if ws_size is too small ----
extern "C" __global__ void __launch_bounds__(THREADS)
swd_slice(const float* __restrict__ x, const float* __restrict__ y,
          const float* __restrict__ proj, float* __restrict__ w2) {
  extern __shared__ float s[];
  __shared__ float wsum[THREADS / 64];
  const int slice = blockIdx.x;
  const int p  = slice % Pp;
  const int bc = slice / Pp;
  const int tid = threadIdx.x;
  const float t0 = proj[2 * p];
  const float t1 = proj[2 * p + 1];
  float v[VPT], sx[VPT];
  project_slice((const float4*)(x + (size_t)bc * Nn * 2), t0, t1, tid, v);
  sort_dist(v, s, tid);
#pragma unroll
  for (int r = 0; r < VPT; r++) sx[r] = v[r];
  project_slice((const float4*)(y + (size_t)bc * Nn * 2), t0, t1, tid, v);
  sort_dist(v, s, tid);
  float acc = 0.f;
#pragma unroll
  for (int r = 0; r < VPT; r++) {
    float d = sx[r] - v[r];
    acc = fmaf(d, d, acc);
  }
#pragma unroll
  for (int off = 32; off > 0; off >>= 1)
    acc += __shfl_down(acc, off, 64);
  if ((tid & 63) == 0) wsum[tid >> 6] = acc;
  __syncthreads();
  if (tid == 0) {
    float t = 0.f;
#pragma unroll
    for (int w = 0; w < THREADS / 64; w++) t += wsum[w];
    w2[slice] = t * (1.0f / Nn);
  }
}

extern "C" __global__ void swd_final(const float* __restrict__ w2,
                                     float* __restrict__ out) {
  __shared__ float sred[Bb * Cc];
  int t = threadIdx.x;
  if (t < Bb * Cc) {
    float sum = 0.f;
    for (int p = 0; p < Pp; p++) sum += w2[t * Pp + p];
    sred[t] = sqrtf(sum * (1.0f / Pp));
  }
  __syncthreads();
  if (t == 0) {
    float a = 0.f;
    for (int i = 0; i < Bb * Cc; i++) a += sred[i];
    out[0] = a * (1.0f / (Bb * Cc));
  }
}

extern "C" void kernel_launch(void* const* d_in, const int* in_sizes, int n_in,
                              void* d_out, int out_size, void* d_ws, size_t ws_size,
                              hipStream_t stream) {
  const float* x    = (const float*)d_in[0];
  const float* y    = (const float*)d_in[1];
  const float* proj = (const float*)d_in[2];
  float* w2  = (float*)d_ws;                       // first 8KB of scratch
  float* xs  = (float*)((char*)d_ws + W2_BYTES);   // sorted-X staging
  float* out = (float*)d_out;

  const size_t lds = (size_t)LDS_FLOATS * sizeof(float);  // 132 KB
  (void)hipFuncSetAttribute((const void*)swd_sortx,
                            hipFuncAttributeMaxDynamicSharedMemorySize, (int)lds);
  (void)hipFuncSetAttribute((const void*)swd_sorty,
                            hipFuncAttributeMaxDynamicSharedMemorySize, (int)lds);
  (void)hipFuncSetAttribute((const void*)swd_slice,
                            hipFuncAttributeMaxDynamicSharedMemorySize, (int)lds);

  const size_t slice_bytes = (size_t)Nn * sizeof(float);
  const size_t avail = ws_size > W2_BYTES ? ws_size - W2_BYTES : 0;
  int chunk = (int)(avail / slice_bytes);
  if (chunk > SLICES) chunk = SLICES;

  if (chunk >= 1) {
    for (int base = 0; base < SLICES; base += chunk) {
      int n = SLICES - base < chunk ? SLICES - base : chunk;
      hipLaunchKernelGGL(swd_sortx, dim3(n), dim3(THREADS), lds, stream,
                         x, proj, xs, base);
      hipLaunchKernelGGL(swd_sorty, dim3(n), dim3(THREADS), lds, stream,
                         y, proj, xs, w2, base);
    }
  } else {
    hipLaunchKernelGGL(swd_slice, dim3(SLICES), dim3(THREADS), lds, stream,
                       x, y, proj, w2);
  }
  hipLaunchKernelGGL(swd_final, dim3(1), dim3(64), 0, stream, w2, out);
}

// Round 8
// 1305.387 us; speedup vs baseline: 1.5906x; 1.0060x over previous
//
#include <hip/hip_runtime.h>
#include <math.h>

// Sliced Wasserstein-2: for each (b,c,p): W2^2 = mean_i (sort(X@theta_p) - sort(Y@theta_p))^2
// loss = mean_{b,c} sqrt(mean_p W2^2)
//
// R8: occupancy 1 -> 2 blocks/CU. R7 analysis: DS busy ~41%, VALU 64%, 16
// barriers/sort stalling all 16 resident waves together -> latency-bound.
// Shrink LDS 132KB -> 66KB (16K-float staging + pad) by chunking the m=64
// exchange and the high-merge transposes; a thread's L0 row lives entirely in
// one 16K half (r2 = tid>>5 is constant per row), so 4-phase chunked
// transposes need only t[16] extra regs (peak live ~60 <= 64 cap, no spill).

namespace {
constexpr int Bb = 8, Cc = 4, Nn = 32768, Pp = 50;
constexpr int THREADS = 1024;
constexpr int VPT = 32;                    // values per thread
constexpr int SLICES = Bb * Cc * Pp;       // 1600
constexpr size_t W2_BYTES = 8192;          // w2[1600] rounded up
constexpr int CHUNK = 16384;               // floats per staging chunk
constexpr int LDS_FLOATS = CHUNK + (CHUNK >> 5);  // 16896 = 66KB padded
}

__device__ __forceinline__ void ce(float& a, float& b, bool up) {
  float lo = fminf(a, b);
  float hi = fmaxf(a, b);
  a = up ? lo : hi;
  b = up ? hi : lo;
}

__device__ __forceinline__ float dpp_xor(float x, int ctrl_sel) {
  // 0xB1 = quad_perm(1,0,3,2) = xor1; 0x4E = quad_perm(2,3,0,1) = xor2
  int i = ctrl_sel == 0xB1
    ? __builtin_amdgcn_update_dpp(0, __float_as_int(x), 0xB1, 0xF, 0xF, true)
    : __builtin_amdgcn_update_dpp(0, __float_as_int(x), 0x4E, 0xF, 0xF, true);
  return __int_as_float(i);
}

// cross-lane CE stage with xor-mask M (M=1,2 via DPP; M>=4 via ds_bpermute)
template<int M>
__device__ __forceinline__ void stage_xlane(float v[VPT], int tid, bool up) {
  const bool keepMin = (up == ((tid & M) == 0));
  if constexpr (M == 1 || M == 2) {
    constexpr int ctrl = (M == 1) ? 0xB1 : 0x4E;
#pragma unroll
    for (int r = 0; r < VPT; r++) {
      float o = dpp_xor(v[r], ctrl);
      v[r] = keepMin ? fminf(v[r], o) : fmaxf(v[r], o);
    }
  } else {
    const int addr = (((tid & 63) ^ M) << 2);
#pragma unroll
    for (int r = 0; r < VPT; r++) {
      float o = __int_as_float(
          __builtin_amdgcn_ds_bpermute(addr, __float_as_int(v[r])));
      v[r] = keepMin ? fminf(v[r], o) : fmaxf(v[r], o);
    }
  }
}

// in-register tail (stages j=16..1), direction uniform per thread: sign-flip trick
__device__ __forceinline__ void tail_inreg(float v[VPT], bool up) {
  const unsigned flip = up ? 0u : 0x80000000u;
#pragma unroll
  for (int r = 0; r < VPT; r++)
    v[r] = __int_as_float(__float_as_int(v[r]) ^ flip);
#pragma unroll
  for (int j = 16; j > 0; j >>= 1) {
#pragma unroll
    for (int r = 0; r < VPT; r++) {
      if (!(r & j)) {
        float a = v[r], b = v[r | j];
        v[r] = fminf(a, b);
        v[r | j] = fmaxf(a, b);
      }
    }
  }
#pragma unroll
  for (int r = 0; r < VPT; r++)
    v[r] = __int_as_float(__float_as_int(v[r]) ^ flip);
}

// wave-local cross stages (m = MTOP..1) + tail, for merge k = 2^A
template<int A, int MTOP>
__device__ __forceinline__ void wave_stages_and_tail(float v[VPT], int tid) {
  const bool up = (A == 15) ? true : ((tid & (1 << (A - 5))) == 0);
  if constexpr (MTOP >= 32) stage_xlane<32>(v, tid, up);
  if constexpr (MTOP >= 16) stage_xlane<16>(v, tid, up);
  if constexpr (MTOP >= 8)  stage_xlane<8>(v, tid, up);
  if constexpr (MTOP >= 4)  stage_xlane<4>(v, tid, up);
  if constexpr (MTOP >= 2)  stage_xlane<2>(v, tid, up);
  if constexpr (MTOP >= 1)  stage_xlane<1>(v, tid, up);
  tail_inreg(v, up);
}

// wave-crossing exchange (xor-mask m on tid), chunked through 16K-float staging
__device__ __forceinline__ void stage_lds(float v[VPT], float* s, int tid,
                                          int m, bool up) {
  const bool keepMin = (up == ((tid & m) == 0));
  const int pt = tid ^ m;
#pragma unroll 1
  for (int c = 0; c < 2; c++) {
    __syncthreads();
#pragma unroll
    for (int rr = 0; rr < 16; rr++) s[rr * THREADS + tid] = v[c * 16 + rr];
    __syncthreads();
#pragma unroll
    for (int rr = 0; rr < 16; rr++) {
      float o = s[rr * THREADS + pt];
      int r = c * 16 + rr;
      v[r] = keepMin ? fminf(v[r], o) : fmaxf(v[r], o);
    }
  }
}

// Merge k=2^A (A=13..15): stages b=A-1..10 in transposed layout L2
// (element i = (r2<<10)|tid, so i[14:10] are register bits, compile-time dirs).
// Transposes are chunked through a 16K-float padded staging region:
// chunk addressing Adr(off) = off + (off>>5) keeps every access <=2-way.
template<int A>
__device__ __forceinline__ void merge_high_l2(float v[VPT], float* s, int tid) {
  float t[16];
  const int grp = tid >> 9;            // which 16K half this thread's L0 row is in
  const int base = tid * VPT;
  // ---- forward transpose L0 -> L2 ----
  __syncthreads();
  if (grp == 0) {
#pragma unroll
    for (int r = 0; r < VPT; r++) { int i = base + r; s[i + (i >> 5)] = v[r]; }
  }
  __syncthreads();
#pragma unroll
  for (int r2 = 0; r2 < 16; r2++) { int i = (r2 << 10) | tid; t[r2] = s[i + (i >> 5)]; }
  __syncthreads();
  if (grp == 1) {
#pragma unroll
    for (int r = 0; r < VPT; r++) { int i = base + r - CHUNK; s[i + (i >> 5)] = v[r]; }
  }
  __syncthreads();
#pragma unroll
  for (int r2 = 16; r2 < VPT; r2++) { int i = ((r2 - 16) << 10) | tid; v[r2] = s[i + (i >> 5)]; }
#pragma unroll
  for (int r2 = 0; r2 < 16; r2++) v[r2] = t[r2];
  // ---- stages b = A-1 .. 10 (register bits A-11..0), compile-time dirs ----
#pragma unroll
  for (int bb = A - 11; bb >= 0; bb--) {
    const int j = 1 << bb;
#pragma unroll
    for (int r2 = 0; r2 < VPT; r2++) {
      if (!(r2 & j)) {
        bool upv = (A == 15) ? true : (((r2 >> (A - 10)) & 1) == 0);
        ce(v[r2], v[r2 | j], upv);
      }
    }
  }
  // ---- backward transpose L2 -> L0 ----
  __syncthreads();
#pragma unroll
  for (int r2 = 0; r2 < 16; r2++) { int i = (r2 << 10) | tid; s[i + (i >> 5)] = v[r2]; }
  __syncthreads();
  if (grp == 0) {                      // full L0 row is in chunk0
#pragma unroll
    for (int r = 0; r < 16; r++) { int i = base + r; v[r] = s[i + (i >> 5)]; }
#pragma unroll
    for (int r = 16; r < VPT; r++) { int i = base + r; t[r - 16] = s[i + (i >> 5)]; }
  }
  __syncthreads();
#pragma unroll
  for (int r2 = 16; r2 < VPT; r2++) { int i = ((r2 - 16) << 10) | tid; s[i + (i >> 5)] = v[r2]; }
  __syncthreads();
  if (grp == 1) {                      // full L0 row is in chunk1
#pragma unroll
    for (int r = 0; r < 16; r++) { int i = base + r - CHUNK; v[r] = s[i + (i >> 5)]; }
#pragma unroll
    for (int r = 16; r < VPT; r++) { int i = base + r - CHUNK; t[r - 16] = s[i + (i >> 5)]; }
  }
#pragma unroll
  for (int r = 16; r < VPT; r++) v[r] = t[r - 16];
}

// Full distributed bitonic sort: rank of v[r] on thread tid is tid*32 + r.
__device__ __forceinline__ void sort_dist(float v[VPT], float* s, int tid) {
  // merges a=1..4 (k=2..16): in-register, compile-time directions
#pragma unroll
  for (int k = 2; k <= 16; k <<= 1) {
#pragma unroll
    for (int j = k >> 1; j > 0; j >>= 1) {
#pragma unroll
      for (int r = 0; r < VPT; r++)
        if (!(r & j)) ce(v[r], v[r | j], (r & k) == 0);
    }
  }
  // a=5 (k=32): dir = tid bit0, all stages in-register
  tail_inreg(v, (tid & 1) == 0);
  // a=6..11: wave-local exchanges + tail
  wave_stages_and_tail<6, 1>(v, tid);
  wave_stages_and_tail<7, 2>(v, tid);
  wave_stages_and_tail<8, 4>(v, tid);
  wave_stages_and_tail<9, 8>(v, tid);
  wave_stages_and_tail<10, 16>(v, tid);
  wave_stages_and_tail<11, 32>(v, tid);
  // a=12: one wave-crossing stage (m=64), then wave-local
  stage_lds(v, s, tid, 64, (tid & 128) == 0);
  wave_stages_and_tail<12, 32>(v, tid);
  // a=13..15: transposed high stages, then wave-local
  merge_high_l2<13>(v, s, tid);
  wave_stages_and_tail<13, 16>(v, tid);
  merge_high_l2<14>(v, s, tid);
  wave_stages_and_tail<14, 16>(v, tid);
  merge_high_l2<15>(v, s, tid);
  wave_stages_and_tail<15, 16>(v, tid);
}

__device__ __forceinline__ void project_slice(const float4* base, float t0, float t1,
                                              int tid, float v[VPT]) {
#pragma unroll
  for (int q = 0; q < VPT / 2; q++) {
    float4 u = base[tid * (VPT / 2) + q];
    v[2 * q]     = fmaf(u.x, t0, u.y * t1);
    v[2 * q + 1] = fmaf(u.z, t0, u.w * t1);
  }
}

// ---- kernel A: sort X slice, stage sorted run in scratch ----
extern "C" __global__ void __launch_bounds__(THREADS)
swd_sortx(const float* __restrict__ x, const float* __restrict__ proj,
          float* __restrict__ xs, int slice_base) {
  extern __shared__ float s[];
  const int slice = slice_base + blockIdx.x;
  const int p  = slice % Pp;
  const int bc = slice / Pp;
  const int tid = threadIdx.x;
  const float t0 = proj[2 * p];
  const float t1 = proj[2 * p + 1];
  float v[VPT];
  project_slice((const float4*)(x + (size_t)bc * Nn * 2), t0, t1, tid, v);
  sort_dist(v, s, tid);
  float4* o = (float4*)(xs + (size_t)blockIdx.x * Nn + tid * VPT);
#pragma unroll
  for (int q = 0; q < VPT / 4; q++)
    o[q] = make_float4(v[4 * q], v[4 * q + 1], v[4 * q + 2], v[4 * q + 3]);
}

// ---- kernel B: sort Y slice, diff against staged sorted X, reduce ----
extern "C" __global__ void __launch_bounds__(THREADS)
swd_sorty(const float* __restrict__ y, const float* __restrict__ proj,
          const float* __restrict__ xs, float* __restrict__ w2, int slice_base) {
  extern __shared__ float s[];
  __shared__ float wsum[THREADS / 64];
  const int slice = slice_base + blockIdx.x;
  const int p  = slice % Pp;
  const int bc = slice / Pp;
  const int tid = threadIdx.x;
  const float t0 = proj[2 * p];
  const float t1 = proj[2 * p + 1];
  float v[VPT];
  project_slice((const float4*)(y + (size_t)bc * Nn * 2), t0, t1, tid, v);
  sort_dist(v, s, tid);

  const float4* xr = (const float4*)(xs + (size_t)blockIdx.x * Nn + tid * VPT);
  float acc = 0.f;
#pragma unroll
  for (int q = 0; q < VPT / 4; q++) {
    float4 u = xr[q];
    float d0 = u.x - v[4 * q];
    float d1 = u.y - v[4 * q + 1];
    float d2 = u.z - v[4 * q + 2];
    float d3 = u.w - v[4 * q + 3];
    acc = fmaf(d0, d0, acc);
    acc = fmaf(d1, d1, acc);
    acc = fmaf(d2, d2, acc);
    acc = fmaf(d3, d3, acc);
  }
#pragma unroll
  for (int off = 32; off > 0; off >>= 1)
    acc += __shfl_down(acc, off, 64);
  if ((tid & 63) == 0) wsum[tid >> 6] = acc;
  __syncthreads();
  if (tid == 0) {
    float t = 0.f;
#pragma unroll
    for (int w = 0; w < THREADS / 64; w++) t += wsum[w];
    w2[slice] = t * (1.0f / Nn);
  }
}

// ---- fallback fused kernel: used only if ws_size is too small ----
extern "C" __global__ void __launch_bounds__(THREADS)
swd_slice(const float* __restrict__ x, const float* __restrict__ y,
          const float* __restrict__ proj, float* __restrict__ w2) {
  extern __shared__ float s[];
  __shared__ float wsum[THREADS / 64];
  const int slice = blockIdx.x;
  const int p  = slice % Pp;
  const int bc = slice / Pp;
  const int tid = threadIdx.x;
  const float t0 = proj[2 * p];
  const float t1 = proj[2 * p + 1];
  float v[VPT], sx[VPT];
  project_slice((const float4*)(x + (size_t)bc * Nn * 2), t0, t1, tid, v);
  sort_dist(v, s, tid);
#pragma unroll
  for (int r = 0; r < VPT; r++) sx[r] = v[r];
  project_slice((const float4*)(y + (size_t)bc * Nn * 2), t0, t1, tid, v);
  sort_dist(v, s, tid);
  float acc = 0.f;
#pragma unroll
  for (int r = 0; r < VPT; r++) {
    float d = sx[r] - v[r];
    acc = fmaf(d, d, acc);
  }
#pragma unroll
  for (int off = 32; off > 0; off >>= 1)
    acc += __shfl_down(acc, off, 64);
  if ((tid & 63) == 0) wsum[tid >> 6] = acc;
  __syncthreads();
  if (tid == 0) {
    float t = 0.f;
#pragma unroll
    for (int w = 0; w < THREADS / 64; w++) t += wsum[w];
    w2[slice] = t * (1.0f / Nn);
  }
}

extern "C" __global__ void swd_final(const float* __restrict__ w2,
                                     float* __restrict__ out) {
  __shared__ float sred[Bb * Cc];
  int t = threadIdx.x;
  if (t < Bb * Cc) {
    float sum = 0.f;
    for (int p = 0; p < Pp; p++) sum += w2[t * Pp + p];
    sred[t] = sqrtf(sum * (1.0f / Pp));
  }
  __syncthreads();
  if (t == 0) {
    float a = 0.f;
    for (int i = 0; i < Bb * Cc; i++) a += sred[i];
    out[0] = a * (1.0f / (Bb * Cc));
  }
}

extern "C" void kernel_launch(void* const* d_in, const int* in_sizes, int n_in,
                              void* d_out, int out_size, void* d_ws, size_t ws_size,
                              hipStream_t stream) {
  const float* x    = (const float*)d_in[0];
  const float* y    = (const float*)d_in[1];
  const float* proj = (const float*)d_in[2];
  float* w2  = (float*)d_ws;                       // first 8KB of scratch
  float* xs  = (float*)((char*)d_ws + W2_BYTES);   // sorted-X staging
  float* out = (float*)d_out;

  const size_t lds = (size_t)LDS_FLOATS * sizeof(float);  // 66 KB -> 2 blocks/CU
  (void)hipFuncSetAttribute((const void*)swd_sortx,
                            hipFuncAttributeMaxDynamicSharedMemorySize, (int)lds);
  (void)hipFuncSetAttribute((const void*)swd_sorty,
                            hipFuncAttributeMaxDynamicSharedMemorySize, (int)lds);
  (void)hipFuncSetAttribute((const void*)swd_slice,
                            hipFuncAttributeMaxDynamicSharedMemorySize, (int)lds);

  const size_t slice_bytes = (size_t)Nn * sizeof(float);
  const size_t avail = ws_size > W2_BYTES ? ws_size - W2_BYTES : 0;
  int chunk = (int)(avail / slice_bytes);
  if (chunk > SLICES) chunk = SLICES;

  if (chunk >= 1) {
    for (int base = 0; base < SLICES; base += chunk) {
      int n = SLICES - base < chunk ? SLICES - base : chunk;
      hipLaunchKernelGGL(swd_sortx, dim3(n), dim3(THREADS), lds, stream,
                         x, proj, xs, base);
      hipLaunchKernelGGL(swd_sorty, dim3(n), dim3(THREADS), lds, stream,
                         y, proj, xs, w2, base);
    }
  } else {
    hipLaunchKernelGGL(swd_slice, dim3(SLICES), dim3(THREADS), lds, stream,
                       x, y, proj, w2);
  }
  hipLaunchKernelGGL(swd_final, dim3(1), dim3(64), 0, stream, w2, out);
}